// Round 4
// baseline (211.690 us; speedup 1.0000x reference)
//
#include <hip/hip_runtime.h>
#include <hip/hip_bf16.h>

// Problem constants
#define B_TOT  4096
#define M_TOT  65536
#define D_V    64
#define KD     96            // 64 (keys) + 32 (0.5*contexts); Q side pre-scaled by log2e
#define BQ     64            // q rows per block (4 waves x 16)
#define BN     32            // keys per inner tile
#define NQT    (B_TOT / BQ)  // 64
#define SHIFT2 23.0f         // fixed softmax shift in exp2 domain

using short8   = __attribute__((ext_vector_type(8))) short;
using floatx4  = __attribute__((ext_vector_type(4))) float;
using int4v    = __attribute__((ext_vector_type(4))) int;

static __device__ __forceinline__ unsigned short f2bf(float f) {
  return __builtin_bit_cast(unsigned short, __float2bfloat16(f));
}

// truncation pack: two f32 -> one dword of bf16 (lo=a, hi=b), single v_perm_b32.
// sel 0x07060302: dst.b0=a.b2 dst.b1=a.b3 (S1=a), dst.b2=b.b2 dst.b3=b.b3 (S0=b).
// Truncation bias cancels in the softmax ratio (verified: absmax 1.5e-5).
static __device__ __forceinline__ int pack_bf16(float a, float b) {
  return (int)__builtin_amdgcn_perm(__builtin_bit_cast(unsigned, b),
                                    __builtin_bit_cast(unsigned, a),
                                    0x07060302u);
}

static __device__ __forceinline__ floatx4 mfma16(short8 a, short8 b, floatx4 c) {
  return __builtin_amdgcn_mfma_f32_16x16x32_bf16(a, b, c, 0, 0, 0);
}

#define LOG2E 1.4426950408889634f

// ---- fused prep kernel ------------------------------------------------------
// blocks [0,1024): kc2   [1024,2048): vt2   [2048,3584): qc   [3584,3840): bias

#define NB_K 1024
#define NB_V 1024
#define NB_Q 1536
#define NB_B 256

__global__ __launch_bounds__(256) void
prep_all(const float* __restrict__ q, const float* __restrict__ ctx,
         const float* __restrict__ keys, const float* __restrict__ ctxs,
         const float* __restrict__ vals, const float* __restrict__ ts,
         const int* __restrict__ used,
         unsigned short* __restrict__ qc, unsigned short* __restrict__ kc2,
         unsigned short* __restrict__ vt2, float* __restrict__ bias)
{
  __shared__ float sbuf[64 * 65 + 64 * 33];
  const int bid = blockIdx.x;
  const int t = threadIdx.x;

  if (bid < NB_K) {
    // K+context in MFMA fragment-linear order (A-operand of S^T = K*Q^T):
    // kc2[g][c][lane][8], c = nt*3+s; elem = Kc[m=g*64+nt*16+(lane&15)][kk=s*32+(lane>>4)*8+j]
    float* lk = sbuf;               // [64][65]
    float* lx = sbuf + 64 * 65;     // [64][33]
    const int g = bid;
    const floatx4* kb4 = reinterpret_cast<const floatx4*>(keys + (size_t)g * 64 * 64);
    const floatx4* xb4 = reinterpret_cast<const floatx4*>(ctxs + (size_t)g * 64 * 32);
#pragma unroll
    for (int i = 0; i < 4; ++i) {
      int idx4 = i * 256 + t;            // 1024 float4s, 16 per row
      floatx4 v = kb4[idx4];
      int row = idx4 >> 4, col = (idx4 & 15) * 4;
      lk[row * 65 + col + 0] = v[0];
      lk[row * 65 + col + 1] = v[1];
      lk[row * 65 + col + 2] = v[2];
      lk[row * 65 + col + 3] = v[3];
    }
#pragma unroll
    for (int i = 0; i < 2; ++i) {
      int idx4 = i * 256 + t;            // 512 float4s, 8 per row
      floatx4 v = xb4[idx4];
      int row = idx4 >> 3, col = (idx4 & 7) * 4;
      lx[row * 33 + col + 0] = v[0];
      lx[row * 33 + col + 1] = v[1];
      lx[row * 33 + col + 2] = v[2];
      lx[row * 33 + col + 3] = v[3];
    }
    __syncthreads();
    unsigned short* outp = kc2 + (size_t)g * 6144;
#pragma unroll
    for (int p = 0; p < 3; ++p) {
      int o = p * 2048 + t * 8;
      int c = o >> 9;
      int lane = (o >> 3) & 63;
      int lqq = lane >> 4, lcc = lane & 15;
      int nt = c / 3, s = c - nt * 3;
      int ml = nt * 16 + lcc;
      short8 v;
#pragma unroll
      for (int j = 0; j < 8; ++j) {
        int kk = s * 32 + lqq * 8 + j;
        float f = (kk < 64) ? lk[ml * 65 + kk] : lx[ml * 33 + (kk - 64)];
        v[j] = (short)f2bf(f);
      }
      *reinterpret_cast<short8*>(outp + o) = v;
    }
  } else if (bid < NB_K + NB_V) {
    // V fragment-linear (B-operand of P*V), with the key-permutation baked in
    // so the packed exp2 output IS the PV A-fragment:
    //   pi(lq*8+j) = (j<4) ? lq*4+j : 16 + lq*4 + (j-4)
    // vt2[g][c2][lane][8], c2 = h*4+nd;
    // elem = V[m = g*64 + h*32 + pi(lq*8+j)][d = nd*16+(lane&15)]
    float* lv = sbuf;               // [64][65]
    const int g = bid - NB_K;
    const floatx4* vb4 = reinterpret_cast<const floatx4*>(vals + (size_t)g * 64 * 64);
#pragma unroll
    for (int i = 0; i < 4; ++i) {
      int idx4 = i * 256 + t;
      floatx4 v = vb4[idx4];
      int row = idx4 >> 4, col = (idx4 & 15) * 4;
      lv[row * 65 + col + 0] = v[0];
      lv[row * 65 + col + 1] = v[1];
      lv[row * 65 + col + 2] = v[2];
      lv[row * 65 + col + 3] = v[3];
    }
    __syncthreads();
    unsigned short* outp = vt2 + (size_t)g * 4096;
#pragma unroll
    for (int p = 0; p < 2; ++p) {
      int o = p * 2048 + t * 8;
      int c2 = o >> 9;
      int lane = (o >> 3) & 63;
      int lqq = lane >> 4, lcc = lane & 15;
      int h = c2 >> 2, nd = c2 & 3;
      short8 w;
#pragma unroll
      for (int j = 0; j < 8; ++j) {
        int mloc = h * 32 + ((j < 4) ? (lqq * 4 + j) : (16 + lqq * 4 + (j - 4)));
        w[j] = (short)f2bf(lv[mloc * 65 + nd * 16 + lcc]);
      }
      *reinterpret_cast<short8*>(outp + o) = w;
    }
  } else if (bid < NB_K + NB_V + NB_Q) {
    int tt = (bid - NB_K - NB_V) * 256 + t;     // 4096*96
    int b = tt / KD, j = tt % KD;
    float v = (j < 64) ? q[b * 64 + j] : 0.5f * ctx[b * 32 + (j - 64)];
    qc[tt] = f2bf(v * LOG2E);
  } else {
    int m = (bid - NB_K - NB_V - NB_Q) * 256 + t;
    bias[m] = used[m] ? (LOG2E * 0.3f * __expf(-0.1f * (1.0f - ts[m])) - SHIFT2) : -1e9f;
  }
}

// ---- flash attention main kernel -------------------------------------------
// grid (NQT=64, NC); block 256 = 4 waves; each wave owns 16 q rows (1 B-frag).
// BN=32 keys per iter; LDS = 2 x 10240 B = 20480 B -> 8 blocks/CU, 32 waves/CU
// (100% static occupancy). Total MFMA/exp work identical to the BQ=128/BN=64
// version; accumulation order of o/lacc bitwise-identical (same 32-key group
// sequence). Software pipeline unchanged: PV(it-1) runs before the barrier of
// iter it from the still-valid other LDS buffer. Bias (incl. -SHIFT2, mask)
// folded into the QK MFMA C-initializer.

template<int NC>
__global__ __launch_bounds__(256, 8) void
flash_kernel(const unsigned short* __restrict__ qc,
             const unsigned short* __restrict__ kc2,
             const unsigned short* __restrict__ vt2,
             const float* __restrict__ bias,
             float* __restrict__ opart, float* __restrict__ lpart)
{
  constexpr int MC  = M_TOT / NC;      // keys per block
  constexpr int NIT = MC / BN;         // 64 for NC=32
  __shared__ __align__(16) unsigned short lds_kv[2 * 5120];  // 20480 B
  const int qt    = blockIdx.x;
  const int chunk = blockIdx.y;
  const int tid   = threadIdx.x;
  const int w     = tid >> 6;
  const int lane  = tid & 63;
  const int lq    = lane >> 4;
  const int lc    = lane & 15;

  floatx4 zero; zero[0] = 0.f; zero[1] = 0.f; zero[2] = 0.f; zero[3] = 0.f;

  // Q fragment (B-operand): q-rows qt*64 + w*16 + lc
  short8 qf[3];
  {
    const unsigned short* qrp = qc + (size_t)(qt * BQ + w * 16 + lc) * KD + lq * 8;
    qf[0] = *reinterpret_cast<const short8*>(qrp);
    qf[1] = *reinterpret_cast<const short8*>(qrp + 32);
    qf[2] = *reinterpret_cast<const short8*>(qrp + 64);
  }

  short8 ones;
#pragma unroll
  for (int i = 0; i < 8; ++i) ones[i] = (short)0x3F80;  // bf16 1.0

  const int g0 = chunk * (MC / 64);
  const float* bptr = bias + chunk * MC + lq * 4;

  // cooperative stage of one 32-key half-group: 10 x 1KB pieces.
  // waves 0,1 take 3 pieces; waves 2,3 take 2 (j = w + j5*4 < 10).
  auto stage = [&](int it, int buf) {
    const int g = g0 + (it >> 1);
    const int h = it & 1;
    const unsigned short* kg = kc2 + (size_t)g * 6144 + h * 3072;
    const unsigned short* vg = vt2 + (size_t)g * 4096 + h * 2048;
    unsigned short* lb = lds_kv + buf * 5120;
#pragma unroll
    for (int j5 = 0; j5 < 3; ++j5) {
      int j = w + j5 * 4;
      if (j < 10) {
        const unsigned short* src = (j < 6) ? (kg + j * 512) : (vg + (j - 6) * 512);
        __builtin_amdgcn_global_load_lds(
            (const __attribute__((address_space(1))) void*)(src + lane * 8),
            (__attribute__((address_space(3))) void*)(lb + j * 512),
            16, 0, 0);
      }
    }
  };

  floatx4 o[4];
#pragma unroll
  for (int nd = 0; nd < 4; ++nd) o[nd] = zero;
  floatx4 lacc = zero;
  int4v pk;

  // QK + exp2 + pack phase (fills pk; accumulates row sums via ones-MFMA)
  auto qk_phase = [&](const unsigned short* lb, const float* bp) {
#pragma unroll
    for (int l = 0; l < 2; ++l) {
      short8 k0 = *reinterpret_cast<const short8*>(lb + (l * 3 + 0) * 512 + lane * 8);
      short8 k1 = *reinterpret_cast<const short8*>(lb + (l * 3 + 1) * 512 + lane * 8);
      short8 k2 = *reinterpret_cast<const short8*>(lb + (l * 3 + 2) * 512 + lane * 8);
      floatx4 b4 = *reinterpret_cast<const floatx4*>(bp + l * 16);
      floatx4 acc = b4;
      acc = mfma16(k0, qf[0], acc);
      acc = mfma16(k1, qf[1], acc);
      acc = mfma16(k2, qf[2], acc);
      float p0 = __builtin_amdgcn_exp2f(acc[0]);
      float p1 = __builtin_amdgcn_exp2f(acc[1]);
      float p2 = __builtin_amdgcn_exp2f(acc[2]);
      float p3 = __builtin_amdgcn_exp2f(acc[3]);
      pk[l * 2]     = pack_bf16(p0, p1);
      pk[l * 2 + 1] = pack_bf16(p2, p3);
    }
    lacc = mfma16(__builtin_bit_cast(short8, pk), ones, lacc);
  };

  // PV phase for the pk currently in registers, V frags from given buffer
  auto pv_phase = [&](const unsigned short* lb) {
#pragma unroll
    for (int nd = 0; nd < 4; ++nd) {
      short8 v0 = *reinterpret_cast<const short8*>(lb + 3072 + nd * 512 + lane * 8);
      o[nd] = mfma16(__builtin_bit_cast(short8, pk), v0, o[nd]);
    }
  };

  // prologue
  stage(0, 0);
  __syncthreads();                  // stage(0) landed
  stage(1, 1);
  qk_phase(lds_kv, bptr);
  bptr += BN;

#pragma unroll 1
  for (int it = 1; it < NIT; ++it) {
    // PV for iter it-1: buffer (it-1)&1 still valid (stage(it+1) not yet issued)
    pv_phase(lds_kv + ((it - 1) & 1) * 5120);
    __syncthreads();               // drains PV ds_reads + stage(it) vmcnt
    if (it + 1 < NIT) stage(it + 1, (it + 1) & 1);
    qk_phase(lds_kv + (it & 1) * 5120, bptr);
    bptr += BN;
  }
  pv_phase(lds_kv + ((NIT - 1) & 1) * 5120);

  // epilogue: write partial O and l
  const int pb = qt * NC + chunk;
  float* op = opart + (size_t)pb * BQ * D_V;
  const int rbase = w * 16 + lq * 4;
#pragma unroll
  for (int nd = 0; nd < 4; ++nd)
#pragma unroll
    for (int r = 0; r < 4; ++r)
      op[(rbase + r) * D_V + nd * 16 + lc] = o[nd][r];
  // lacc C-layout: lane (lq,lc) reg r holds l[q-row = lq*4+r] (same across lc)
  if (lc == 0) {
    float* lp = lpart + (size_t)pb * BQ;
#pragma unroll
    for (int r = 0; r < 4; ++r) lp[rbase + r] = lacc[r];
  }
}

// ---- final reduction (float4-vectorized) ------------------------------------

template<int NC>
__global__ void reduce_out(const float* __restrict__ opart, const float* __restrict__ lpart,
                           float* __restrict__ out) {
  int t = blockIdx.x * 256 + threadIdx.x;   // 65536 float4s total
  int d4 = t & 15;
  int b = t >> 4;            // q-row 0..4095
  int qt = b >> 6, r = b & 63;              // BQ = 64
  const floatx4* op4 = reinterpret_cast<const floatx4*>(opart);
  floatx4 os; os[0] = 0.f; os[1] = 0.f; os[2] = 0.f; os[3] = 0.f;
  float ls = 0.f;
#pragma unroll
  for (int c = 0; c < NC; ++c) {
    int row = (qt * NC + c) * BQ + r;
    os += op4[(size_t)row * 16 + d4];
    ls += lpart[row];
  }
  float inv = 1.0f / ls;
  reinterpret_cast<floatx4*>(out)[t] = os * inv;
}

// ---- launcher ---------------------------------------------------------------

template<int NC>
static void launch_all(const float* query, const float* context, const float* keys,
                       const float* values, const float* contexts, const float* ts,
                       const int* used, float* out, char* ws, hipStream_t stream) {
  unsigned short* qc  = (unsigned short*)ws;  ws += (size_t)B_TOT * KD * 2;
  unsigned short* kc2 = (unsigned short*)ws;  ws += (size_t)M_TOT * KD * 2;
  unsigned short* vt2 = (unsigned short*)ws;  ws += (size_t)D_V * M_TOT * 2;
  float* bias  = (float*)ws;                  ws += (size_t)M_TOT * 4;
  float* opart = (float*)ws;                  ws += (size_t)NC * B_TOT * D_V * 4;
  float* lpart = (float*)ws;

  prep_all<<<NB_K + NB_V + NB_Q + NB_B, 256, 0, stream>>>(
      query, context, keys, contexts, values, ts, used, qc, kc2, vt2, bias);

  dim3 grid(NQT, NC);
  flash_kernel<NC><<<grid, 256, 0, stream>>>(qc, kc2, vt2, bias, opart, lpart);

  reduce_out<NC><<<(B_TOT * D_V / 4) / 256, 256, 0, stream>>>(opart, lpart, out);
}

extern "C" void kernel_launch(void* const* d_in, const int* in_sizes, int n_in,
                              void* d_out, int out_size, void* d_ws, size_t ws_size,
                              hipStream_t stream) {
  const float* query    = (const float*)d_in[0];
  const float* context  = (const float*)d_in[1];
  const float* keys     = (const float*)d_in[2];
  const float* values   = (const float*)d_in[3];
  const float* contexts = (const float*)d_in[4];
  const float* ts       = (const float*)d_in[5];
  const int*   used     = (const int*)d_in[6];
  float* out = (float*)d_out;
  char* ws = (char*)d_ws;

  const size_t fixed = (size_t)B_TOT * KD * 2 + (size_t)M_TOT * KD * 2 +
                       (size_t)D_V * M_TOT * 2 + (size_t)M_TOT * 4;
  const size_t need32 = fixed + 32ull * ((size_t)B_TOT * D_V * 4 + (size_t)B_TOT * 4);

  if (ws_size >= need32)
    launch_all<32>(query, context, keys, values, contexts, ts, used, out, ws, stream);
  else
    launch_all<16>(query, context, keys, values, contexts, ts, used, out, ws, stream);
}

// Round 5
// 181.121 us; speedup vs baseline: 1.1688x; 1.1688x over previous
//
#include <hip/hip_runtime.h>
#include <hip/hip_bf16.h>

// Problem constants
#define B_TOT  4096
#define M_TOT  65536
#define D_V    64
#define KD     96            // 64 (keys) + 32 (0.5*contexts); Q side pre-scaled by log2e
#define BQ     128           // q rows per block (4 waves x 32)
#define BN     64            // keys per inner tile
#define NQT    (B_TOT / BQ)  // 32
#define SHIFT2 23.0f         // fixed softmax shift in exp2 domain

using short8   = __attribute__((ext_vector_type(8))) short;
using floatx4  = __attribute__((ext_vector_type(4))) float;
using int4v    = __attribute__((ext_vector_type(4))) int;

static __device__ __forceinline__ unsigned short f2bf(float f) {
  return __builtin_bit_cast(unsigned short, __float2bfloat16(f));
}

// truncation pack: two f32 -> one dword of bf16 (lo=a, hi=b), single v_perm_b32.
// sel 0x07060302: dst.b0=a.b2 dst.b1=a.b3 (S1=a), dst.b2=b.b2 dst.b3=b.b3 (S0=b).
// Truncation bias cancels in the softmax ratio (verified: absmax 1.5e-5).
static __device__ __forceinline__ int pack_bf16(float a, float b) {
  return (int)__builtin_amdgcn_perm(__builtin_bit_cast(unsigned, b),
                                    __builtin_bit_cast(unsigned, a),
                                    0x07060302u);
}

static __device__ __forceinline__ floatx4 mfma16(short8 a, short8 b, floatx4 c) {
  return __builtin_amdgcn_mfma_f32_16x16x32_bf16(a, b, c, 0, 0, 0);
}

#define LOG2E 1.4426950408889634f

// ---- fused prep kernel ------------------------------------------------------
// blocks [0,1024): kc2   [1024,2048): vt2   [2048,3584): qc   [3584,3840): bias

#define NB_K 1024
#define NB_V 1024
#define NB_Q 1536
#define NB_B 256

__global__ __launch_bounds__(256) void
prep_all(const float* __restrict__ q, const float* __restrict__ ctx,
         const float* __restrict__ keys, const float* __restrict__ ctxs,
         const float* __restrict__ vals, const float* __restrict__ ts,
         const int* __restrict__ used,
         unsigned short* __restrict__ qc, unsigned short* __restrict__ kc2,
         unsigned short* __restrict__ vt2, float* __restrict__ bias)
{
  __shared__ float sbuf[64 * 65 + 64 * 33];
  const int bid = blockIdx.x;
  const int t = threadIdx.x;

  if (bid < NB_K) {
    // K+context in MFMA fragment-linear order (A-operand of S^T = K*Q^T):
    // kc2[g][c][lane][8], c = nt*3+s; elem = Kc[m=g*64+nt*16+(lane&15)][kk=s*32+(lane>>4)*8+j]
    float* lk = sbuf;               // [64][65]
    float* lx = sbuf + 64 * 65;     // [64][33]
    const int g = bid;
    const floatx4* kb4 = reinterpret_cast<const floatx4*>(keys + (size_t)g * 64 * 64);
    const floatx4* xb4 = reinterpret_cast<const floatx4*>(ctxs + (size_t)g * 64 * 32);
#pragma unroll
    for (int i = 0; i < 4; ++i) {
      int idx4 = i * 256 + t;            // 1024 float4s, 16 per row
      floatx4 v = kb4[idx4];
      int row = idx4 >> 4, col = (idx4 & 15) * 4;
      lk[row * 65 + col + 0] = v[0];
      lk[row * 65 + col + 1] = v[1];
      lk[row * 65 + col + 2] = v[2];
      lk[row * 65 + col + 3] = v[3];
    }
#pragma unroll
    for (int i = 0; i < 2; ++i) {
      int idx4 = i * 256 + t;            // 512 float4s, 8 per row
      floatx4 v = xb4[idx4];
      int row = idx4 >> 3, col = (idx4 & 7) * 4;
      lx[row * 33 + col + 0] = v[0];
      lx[row * 33 + col + 1] = v[1];
      lx[row * 33 + col + 2] = v[2];
      lx[row * 33 + col + 3] = v[3];
    }
    __syncthreads();
    unsigned short* outp = kc2 + (size_t)g * 6144;
#pragma unroll
    for (int p = 0; p < 3; ++p) {
      int o = p * 2048 + t * 8;
      int c = o >> 9;
      int lane = (o >> 3) & 63;
      int lqq = lane >> 4, lcc = lane & 15;
      int nt = c / 3, s = c - nt * 3;
      int ml = nt * 16 + lcc;
      short8 v;
#pragma unroll
      for (int j = 0; j < 8; ++j) {
        int kk = s * 32 + lqq * 8 + j;
        float f = (kk < 64) ? lk[ml * 65 + kk] : lx[ml * 33 + (kk - 64)];
        v[j] = (short)f2bf(f);
      }
      *reinterpret_cast<short8*>(outp + o) = v;
    }
  } else if (bid < NB_K + NB_V) {
    // V fragment-linear (B-operand of P*V), with the key-permutation baked in
    // so the packed exp2 output IS the PV A-fragment:
    //   pi(lq*8+j) = (j<4) ? lq*4+j : 16 + lq*4 + (j-4)
    // vt2[g][c2][lane][8], c2 = h*4+nd;
    // elem = V[m = g*64 + h*32 + pi(lq*8+j)][d = nd*16+(lane&15)]
    float* lv = sbuf;               // [64][65]
    const int g = bid - NB_K;
    const floatx4* vb4 = reinterpret_cast<const floatx4*>(vals + (size_t)g * 64 * 64);
#pragma unroll
    for (int i = 0; i < 4; ++i) {
      int idx4 = i * 256 + t;
      floatx4 v = vb4[idx4];
      int row = idx4 >> 4, col = (idx4 & 15) * 4;
      lv[row * 65 + col + 0] = v[0];
      lv[row * 65 + col + 1] = v[1];
      lv[row * 65 + col + 2] = v[2];
      lv[row * 65 + col + 3] = v[3];
    }
    __syncthreads();
    unsigned short* outp = vt2 + (size_t)g * 4096;
#pragma unroll
    for (int p = 0; p < 2; ++p) {
      int o = p * 2048 + t * 8;
      int c2 = o >> 9;
      int lane = (o >> 3) & 63;
      int lqq = lane >> 4, lcc = lane & 15;
      int h = c2 >> 2, nd = c2 & 3;
      short8 w;
#pragma unroll
      for (int j = 0; j < 8; ++j) {
        int mloc = h * 32 + ((j < 4) ? (lqq * 4 + j) : (16 + lqq * 4 + (j - 4)));
        w[j] = (short)f2bf(lv[mloc * 65 + nd * 16 + lcc]);
      }
      *reinterpret_cast<short8*>(outp + o) = w;
    }
  } else if (bid < NB_K + NB_V + NB_Q) {
    int tt = (bid - NB_K - NB_V) * 256 + t;     // 4096*96
    int b = tt / KD, j = tt % KD;
    float v = (j < 64) ? q[b * 64 + j] : 0.5f * ctx[b * 32 + (j - 64)];
    qc[tt] = f2bf(v * LOG2E);
  } else {
    int m = (bid - NB_K - NB_V - NB_Q) * 256 + t;
    bias[m] = used[m] ? (LOG2E * 0.3f * __expf(-0.1f * (1.0f - ts[m])) - SHIFT2) : -1e9f;
  }
}

// ---- flash attention main kernel -------------------------------------------
// grid (NQT, NC); block 256 = 4 waves; each wave owns 32 q rows (2 B-frags).
// K/V staged per block-iter into double-buffered LDS (global_load_lds w=16).
// Software-pipelined: PV(it-1) runs BEFORE the barrier of iter it, using pk
// registers from the previous iteration and the still-valid other LDS buffer.
// S^T = K*Q^T; packed exp2 output IS the PV A-fragment (V rows pre-permuted).
// Row sums via ones-MFMA. Bias (incl. -SHIFT2 and -1e9 mask) is folded into
// the QK MFMA C-initializer. R5: s_setprio(1) around MFMA clusters (T5 —
// independent phase-drifted blocks = the regime where it measured +4-7%),
// bias loads hoisted to phase top.

template<int NC>
__global__ __launch_bounds__(256, 4) void
flash_kernel(const unsigned short* __restrict__ qc,
             const unsigned short* __restrict__ kc2,
             const unsigned short* __restrict__ vt2,
             const float* __restrict__ bias,
             float* __restrict__ opart, float* __restrict__ lpart)
{
  constexpr int MC  = M_TOT / NC;      // keys per block
  constexpr int NIT = MC / BN;         // >= 2
  __shared__ __align__(16) unsigned short lds_kv[2 * 10240];  // 40960 B
  const int qt    = blockIdx.x;
  const int chunk = blockIdx.y;
  const int tid   = threadIdx.x;
  const int w     = tid >> 6;
  const int lane  = tid & 63;
  const int lq    = lane >> 4;
  const int lc    = lane & 15;

  floatx4 zero; zero[0] = 0.f; zero[1] = 0.f; zero[2] = 0.f; zero[3] = 0.f;

  // Q fragments (B-operand): q-rows qt*128 + w*32 + a*16 + lc
  short8 qf[2][3];
#pragma unroll
  for (int a = 0; a < 2; ++a) {
    const unsigned short* qrp = qc + (size_t)(qt * BQ + w * 32 + a * 16 + lc) * KD + lq * 8;
    qf[a][0] = *reinterpret_cast<const short8*>(qrp);
    qf[a][1] = *reinterpret_cast<const short8*>(qrp + 32);
    qf[a][2] = *reinterpret_cast<const short8*>(qrp + 64);
  }

  short8 ones;
#pragma unroll
  for (int i = 0; i < 8; ++i) ones[i] = (short)0x3F80;  // bf16 1.0

  const int g0 = chunk * (MC / 64);
  const float* bptr = bias + chunk * MC + lq * 4;

  // cooperative stage of one 64-key group: 20 x 1KB pieces, 5 per wave
  auto stage = [&](int it, int buf) {
    const unsigned short* kg = kc2 + (size_t)(g0 + it) * 6144;
    const unsigned short* vg = vt2 + (size_t)(g0 + it) * 4096;
    unsigned short* lb = lds_kv + buf * 10240;
#pragma unroll
    for (int j5 = 0; j5 < 5; ++j5) {
      int j = w + j5 * 4;
      const unsigned short* src = (j < 12) ? (kg + j * 512) : (vg + (j - 12) * 512);
      __builtin_amdgcn_global_load_lds(
          (const __attribute__((address_space(1))) void*)(src + lane * 8),
          (__attribute__((address_space(3))) void*)(lb + j * 512),
          16, 0, 0);
    }
  };

  floatx4 o[2][4];
#pragma unroll
  for (int a = 0; a < 2; ++a)
#pragma unroll
    for (int nd = 0; nd < 4; ++nd) o[a][nd] = zero;
  floatx4 lacc[2] = {zero, zero};
  int4v pk[2][2];

  // QK + exp2 + pack phase (fills pk; accumulates row sums via ones-MFMA)
  auto qk_phase = [&](const unsigned short* lb, const float* bp) {
    floatx4 b4v[4];
#pragma unroll
    for (int nt = 0; nt < 4; ++nt)
      b4v[nt] = *reinterpret_cast<const floatx4*>(bp + nt * 16);
#pragma unroll
    for (int nt = 0; nt < 4; ++nt) {
      short8 k0 = *reinterpret_cast<const short8*>(lb + (nt * 3 + 0) * 512 + lane * 8);
      short8 k1 = *reinterpret_cast<const short8*>(lb + (nt * 3 + 1) * 512 + lane * 8);
      short8 k2 = *reinterpret_cast<const short8*>(lb + (nt * 3 + 2) * 512 + lane * 8);
#pragma unroll
      for (int a = 0; a < 2; ++a) {
        floatx4 acc = b4v[nt];
        __builtin_amdgcn_s_setprio(1);
        acc = mfma16(k0, qf[a][0], acc);
        acc = mfma16(k1, qf[a][1], acc);
        acc = mfma16(k2, qf[a][2], acc);
        __builtin_amdgcn_s_setprio(0);
        float p0 = __builtin_amdgcn_exp2f(acc[0]);
        float p1 = __builtin_amdgcn_exp2f(acc[1]);
        float p2 = __builtin_amdgcn_exp2f(acc[2]);
        float p3 = __builtin_amdgcn_exp2f(acc[3]);
        pk[a][nt >> 1][(nt & 1) * 2]     = pack_bf16(p0, p1);
        pk[a][nt >> 1][(nt & 1) * 2 + 1] = pack_bf16(p2, p3);
      }
    }
    __builtin_amdgcn_s_setprio(1);
#pragma unroll
    for (int a = 0; a < 2; ++a) {
      lacc[a] = mfma16(__builtin_bit_cast(short8, pk[a][0]), ones, lacc[a]);
      lacc[a] = mfma16(__builtin_bit_cast(short8, pk[a][1]), ones, lacc[a]);
    }
    __builtin_amdgcn_s_setprio(0);
  };

  // PV phase for the pk currently in registers, V frags from given buffer
  auto pv_phase = [&](const unsigned short* lb) {
    __builtin_amdgcn_s_setprio(1);
#pragma unroll
    for (int nd = 0; nd < 4; ++nd) {
      short8 v0 = *reinterpret_cast<const short8*>(lb + 6144 + nd * 512 + lane * 8);
      short8 v1 = *reinterpret_cast<const short8*>(lb + 6144 + (4 + nd) * 512 + lane * 8);
#pragma unroll
      for (int a = 0; a < 2; ++a) {
        o[a][nd] = mfma16(__builtin_bit_cast(short8, pk[a][0]), v0, o[a][nd]);
        o[a][nd] = mfma16(__builtin_bit_cast(short8, pk[a][1]), v1, o[a][nd]);
      }
    }
    __builtin_amdgcn_s_setprio(0);
  };

  // prologue
  stage(0, 0);
  __syncthreads();                  // stage(0) landed
  stage(1, 1);
  qk_phase(lds_kv, bptr);
  bptr += BN;

#pragma unroll 1
  for (int it = 1; it < NIT; ++it) {
    // PV for iter it-1: buffer (it-1)&1 still valid (stage(it+1) not yet issued)
    pv_phase(lds_kv + ((it - 1) & 1) * 10240);
    __syncthreads();               // drains PV ds_reads + stage(it) vmcnt
    if (it + 1 < NIT) stage(it + 1, (it + 1) & 1);
    qk_phase(lds_kv + (it & 1) * 10240, bptr);
    bptr += BN;
  }
  pv_phase(lds_kv + ((NIT - 1) & 1) * 10240);

  // epilogue: write partial O and l
  const int pb = qt * NC + chunk;
  float* op = opart + (size_t)pb * BQ * D_V;
#pragma unroll
  for (int a = 0; a < 2; ++a) {
    const int rbase = w * 32 + a * 16 + lq * 4;
#pragma unroll
    for (int nd = 0; nd < 4; ++nd)
#pragma unroll
      for (int r = 0; r < 4; ++r)
        op[(rbase + r) * D_V + nd * 16 + lc] = o[a][nd][r];
    // lacc C-layout: lane (lq,lc) reg r holds l[q-row = lq*4+r] (same across lc)
    if (lc == 0) {
      float* lp = lpart + (size_t)pb * BQ;
#pragma unroll
      for (int r = 0; r < 4; ++r) lp[rbase + r] = lacc[a][r];
    }
  }
}

// ---- final reduction (float4-vectorized) ------------------------------------

template<int NC>
__global__ void reduce_out(const float* __restrict__ opart, const float* __restrict__ lpart,
                           float* __restrict__ out) {
  int t = blockIdx.x * 256 + threadIdx.x;   // 65536 float4s total
  int d4 = t & 15;
  int b = t >> 4;            // q-row 0..4095
  int qt = b >> 7, r = b & 127;
  const floatx4* op4 = reinterpret_cast<const floatx4*>(opart);
  floatx4 os; os[0] = 0.f; os[1] = 0.f; os[2] = 0.f; os[3] = 0.f;
  float ls = 0.f;
#pragma unroll
  for (int c = 0; c < NC; ++c) {
    int row = (qt * NC + c) * BQ + r;
    os += op4[(size_t)row * 16 + d4];
    ls += lpart[row];
  }
  float inv = 1.0f / ls;
  reinterpret_cast<floatx4*>(out)[t] = os * inv;
}

// ---- launcher ---------------------------------------------------------------

template<int NC>
static void launch_all(const float* query, const float* context, const float* keys,
                       const float* values, const float* contexts, const float* ts,
                       const int* used, float* out, char* ws, hipStream_t stream) {
  unsigned short* qc  = (unsigned short*)ws;  ws += (size_t)B_TOT * KD * 2;
  unsigned short* kc2 = (unsigned short*)ws;  ws += (size_t)M_TOT * KD * 2;
  unsigned short* vt2 = (unsigned short*)ws;  ws += (size_t)D_V * M_TOT * 2;
  float* bias  = (float*)ws;                  ws += (size_t)M_TOT * 4;
  float* opart = (float*)ws;                  ws += (size_t)NC * B_TOT * D_V * 4;
  float* lpart = (float*)ws;

  prep_all<<<NB_K + NB_V + NB_Q + NB_B, 256, 0, stream>>>(
      query, context, keys, contexts, values, ts, used, qc, kc2, vt2, bias);

  dim3 grid(NQT, NC);
  flash_kernel<NC><<<grid, 256, 0, stream>>>(qc, kc2, vt2, bias, opart, lpart);

  reduce_out<NC><<<(B_TOT * D_V / 4) / 256, 256, 0, stream>>>(opart, lpart, out);
}

extern "C" void kernel_launch(void* const* d_in, const int* in_sizes, int n_in,
                              void* d_out, int out_size, void* d_ws, size_t ws_size,
                              hipStream_t stream) {
  const float* query    = (const float*)d_in[0];
  const float* context  = (const float*)d_in[1];
  const float* keys     = (const float*)d_in[2];
  const float* values   = (const float*)d_in[3];
  const float* contexts = (const float*)d_in[4];
  const float* ts       = (const float*)d_in[5];
  const int*   used     = (const int*)d_in[6];
  float* out = (float*)d_out;
  char* ws = (char*)d_ws;

  const size_t fixed = (size_t)B_TOT * KD * 2 + (size_t)M_TOT * KD * 2 +
                       (size_t)D_V * M_TOT * 2 + (size_t)M_TOT * 4;
  const size_t need32 = fixed + 32ull * ((size_t)B_TOT * D_V * 4 + (size_t)B_TOT * 4);

  if (ws_size >= need32)
    launch_all<32>(query, context, keys, values, contexts, ts, used, out, ws, stream);
  else
    launch_all<16>(query, context, keys, values, contexts, ts, used, out, ws, stream);
}

// Round 6
// 178.687 us; speedup vs baseline: 1.1847x; 1.0136x over previous
//
#include <hip/hip_runtime.h>
#include <hip/hip_bf16.h>

// Problem constants
#define B_TOT  4096
#define M_TOT  65536
#define D_V    64
#define KD     96            // 64 (keys) + 32 (0.5*contexts); Q side pre-scaled by log2e
#define BQ     128           // q rows per block (4 waves x 32)
#define BN     64            // keys per inner tile
#define NQT    (B_TOT / BQ)  // 32
#define SHIFT2 23.0f         // fixed softmax shift in exp2 domain
#define NGRP   1024          // source 64-slot groups
#define NG_PAD 1056          // compacted group capacity (>= NC*ceil(NGRP/NC) for NC=16,32)

using short8   = __attribute__((ext_vector_type(8))) short;
using floatx4  = __attribute__((ext_vector_type(4))) float;
using int4v    = __attribute__((ext_vector_type(4))) int;

static __device__ __forceinline__ unsigned short f2bf(float f) {
  return __builtin_bit_cast(unsigned short, __float2bfloat16(f));
}

// truncation pack: two f32 -> one dword of bf16 (lo=a, hi=b), single v_perm_b32.
// Truncation bias cancels in the softmax ratio (verified: absmax 1.5e-5).
static __device__ __forceinline__ int pack_bf16(float a, float b) {
  return (int)__builtin_amdgcn_perm(__builtin_bit_cast(unsigned, b),
                                    __builtin_bit_cast(unsigned, a),
                                    0x07060302u);
}

static __device__ __forceinline__ floatx4 mfma16(short8 a, short8 b, floatx4 c) {
  return __builtin_amdgcn_mfma_f32_16x16x32_bf16(a, b, c, 0, 0, 0);
}

#define LOG2E 1.4426950408889634f

// ---- kernel 1: count + scan used slots --------------------------------------
// 1 block x 1024 threads. Per-64-group ballot -> masks[g], popc -> cnt; LDS
// Hillis-Steele inclusive scan -> off[g] (exclusive), total -> gtotal.
// Masked slots contribute EXACTLY 0 to softmax (exp2(-1e9) underflows to 0 in
// fp32, same as the reference), so compacting to used slots is numerically
// exact up to fp32 summation order (~1e-7).

__global__ __launch_bounds__(1024) void
scan_used(const int* __restrict__ used, int* __restrict__ off,
          unsigned long long* __restrict__ masks, int* __restrict__ gtotal)
{
  __shared__ int s[NGRP];
  const int t = threadIdx.x;
  const int w = t >> 6, l = t & 63;
#pragma unroll 1
  for (int i = 0; i < 64; ++i) {
    int g = i * 16 + w;
    unsigned long long m = __ballot(used[g * 64 + l] != 0);
    if (l == 0) { masks[g] = m; s[g] = __popcll(m); }
  }
  __syncthreads();
  const int c0 = s[t];
#pragma unroll 1
  for (int st = 1; st < NGRP; st <<= 1) {
    int add = (t >= st) ? s[t - st] : 0;
    __syncthreads();
    s[t] += add;
    __syncthreads();
  }
  off[t] = s[t] - c0;
  if (t == NGRP - 1) *gtotal = s[t];
}

// ---- kernel 2: gather-prep into compacted fragment-linear layouts -----------
// blocks [0, NG_PAD): compacted K/ctx/V/bias dest groups (gather via off+masks)
// blocks [NG_PAD, NG_PAD+NB_Q): qc (unchanged)

#define NB_Q 1536

__global__ __launch_bounds__(256) void
prep2(const float* __restrict__ q, const float* __restrict__ ctx,
      const float* __restrict__ keys, const float* __restrict__ ctxs,
      const float* __restrict__ vals, const float* __restrict__ ts,
      const int* __restrict__ off, const unsigned long long* __restrict__ masks,
      const int* __restrict__ gtotal,
      unsigned short* __restrict__ qc, unsigned short* __restrict__ kc2,
      unsigned short* __restrict__ vt2, float* __restrict__ biasc)
{
  const int bid = blockIdx.x;
  const int t = threadIdx.x;

  if (bid < NG_PAD) {
    __shared__ float lk[64 * 65];    // K rows; reused for V rows
    __shared__ float lx[64 * 33];    // ctx rows
    __shared__ int sidx[64];
    const int gq = bid;              // dest group
    const int total = *gtotal;

    // source index for each of this dest group's 64 slots
    if (t < 64) {
      int mP = gq * 64 + t, src = -1;
      if (mP < total) {
        int lo = 0, hi = NGRP - 1;
#pragma unroll 1
        while (lo < hi) {            // last g with off[g] <= mP
          int mid = (lo + hi + 1) >> 1;
          int ov = off[mid];
          if (ov <= mP) lo = mid; else hi = mid - 1;
        }
        int r = mP - off[lo];
        unsigned long long x = masks[lo];
#pragma unroll 1
        for (int k = 0; k < r; ++k) x &= x - 1;   // select r-th set bit
        src = lo * 64 + (int)__builtin_ctzll(x);
      }
      sidx[t] = src;
    }
    __syncthreads();

    const floatx4* kb4 = reinterpret_cast<const floatx4*>(keys);
    const floatx4* xb4 = reinterpret_cast<const floatx4*>(ctxs);
    const floatx4* vb4 = reinterpret_cast<const floatx4*>(vals);
    floatx4 z4; z4[0] = 0.f; z4[1] = 0.f; z4[2] = 0.f; z4[3] = 0.f;

    // gather K rows (64x64 f32) + ctx rows (64x32 f32); pad rows -> 0
#pragma unroll
    for (int i = 0; i < 4; ++i) {
      int idx4 = i * 256 + t;
      int row = idx4 >> 4, col = idx4 & 15;
      int s = sidx[row];
      floatx4 v = (s >= 0) ? kb4[(size_t)s * 16 + col] : z4;
      lk[row * 65 + col * 4 + 0] = v[0];
      lk[row * 65 + col * 4 + 1] = v[1];
      lk[row * 65 + col * 4 + 2] = v[2];
      lk[row * 65 + col * 4 + 3] = v[3];
    }
#pragma unroll
    for (int i = 0; i < 2; ++i) {
      int idx4 = i * 256 + t;
      int row = idx4 >> 3, col = idx4 & 7;
      int s = sidx[row];
      floatx4 v = (s >= 0) ? xb4[(size_t)s * 8 + col] : z4;
      lx[row * 33 + col * 4 + 0] = v[0];
      lx[row * 33 + col * 4 + 1] = v[1];
      lx[row * 33 + col * 4 + 2] = v[2];
      lx[row * 33 + col * 4 + 3] = v[3];
    }
    __syncthreads();

    // pack kc2 fragment-linear (same mapping as before, dest group gq)
    unsigned short* outk = kc2 + (size_t)gq * 6144;
#pragma unroll
    for (int p = 0; p < 3; ++p) {
      int o = p * 2048 + t * 8;
      int c = o >> 9;
      int lane = (o >> 3) & 63;
      int lqq = lane >> 4, lcc = lane & 15;
      int nt = c / 3, s = c - nt * 3;
      int ml = nt * 16 + lcc;
      short8 v;
#pragma unroll
      for (int j = 0; j < 8; ++j) {
        int kk = s * 32 + lqq * 8 + j;
        float f = (kk < 64) ? lk[ml * 65 + kk] : lx[ml * 33 + (kk - 64)];
        v[j] = (short)f2bf(f);
      }
      *reinterpret_cast<short8*>(outk + o) = v;
    }
    // bias for this dest group (pad -> -1e9 -> exp2 -> 0)
    if (t < 64) {
      int s = sidx[t];
      biasc[gq * 64 + t] =
          (s >= 0) ? (LOG2E * 0.3f * __expf(-0.1f * (1.0f - ts[s])) - SHIFT2)
                   : -1e9f;
    }
    __syncthreads();   // all kc2-pack reads of lk done before V overwrites it

    // gather V rows into lk
#pragma unroll
    for (int i = 0; i < 4; ++i) {
      int idx4 = i * 256 + t;
      int row = idx4 >> 4, col = idx4 & 15;
      int s = sidx[row];
      floatx4 v = (s >= 0) ? vb4[(size_t)s * 16 + col] : z4;
      lk[row * 65 + col * 4 + 0] = v[0];
      lk[row * 65 + col * 4 + 1] = v[1];
      lk[row * 65 + col * 4 + 2] = v[2];
      lk[row * 65 + col * 4 + 3] = v[3];
    }
    __syncthreads();

    // pack vt2 (B-operand of P*V, key-permutation baked in), dest group gq
    unsigned short* outv = vt2 + (size_t)gq * 4096;
#pragma unroll
    for (int p = 0; p < 2; ++p) {
      int o = p * 2048 + t * 8;
      int c2 = o >> 9;
      int lane = (o >> 3) & 63;
      int lqq = lane >> 4, lcc = lane & 15;
      int h = c2 >> 2, nd = c2 & 3;
      short8 wv;
#pragma unroll
      for (int j = 0; j < 8; ++j) {
        int mloc = h * 32 + ((j < 4) ? (lqq * 4 + j) : (16 + lqq * 4 + (j - 4)));
        wv[j] = (short)f2bf(lk[mloc * 65 + nd * 16 + lcc]);
      }
      *reinterpret_cast<short8*>(outv + o) = wv;
    }
  } else {
    int tt = (bid - NG_PAD) * 256 + t;     // 4096*96
    int b = tt / KD, j = tt % KD;
    float v = (j < 64) ? q[b * 64 + j] : 0.5f * ctx[b * 32 + (j - 64)];
    qc[tt] = f2bf(v * LOG2E);
  }
}

// ---- flash attention main kernel -------------------------------------------
// grid (NQT, NC); block 256 = 4 waves; each wave owns 32 q rows (2 B-frags).
// Now runs over the COMPACTED slot stream: NIT = GPC = ceil(Gtot/NC) groups
// per chunk, read from gtotal at runtime (uniform across the grid; grid dims
// static -> graph-capture safe). Pad groups contribute exact zeros.
// Software pipeline + setprio (R5) unchanged.

template<int NC>
__global__ __launch_bounds__(256, 4) void
flash_kernel(const unsigned short* __restrict__ qc,
             const unsigned short* __restrict__ kc2,
             const unsigned short* __restrict__ vt2,
             const float* __restrict__ biasc,
             const int* __restrict__ gtotal,
             float* __restrict__ opart, float* __restrict__ lpart)
{
  __shared__ __align__(16) unsigned short lds_kv[2 * 10240];  // 40960 B
  const int qt    = blockIdx.x;
  const int chunk = blockIdx.y;
  const int tid   = threadIdx.x;
  const int w     = tid >> 6;
  const int lane  = tid & 63;
  const int lq    = lane >> 4;
  const int lc    = lane & 15;

  const int total = *gtotal;
  const int Gtot  = (total + 63) >> 6;
  int GPC = (Gtot + NC - 1) / NC;
  if (GPC < 1) GPC = 1;
  const int NIT = GPC;                 // 64-key tiles for this chunk
  const int g0  = chunk * GPC;

  floatx4 zero; zero[0] = 0.f; zero[1] = 0.f; zero[2] = 0.f; zero[3] = 0.f;

  // Q fragments (B-operand): q-rows qt*128 + w*32 + a*16 + lc
  short8 qf[2][3];
#pragma unroll
  for (int a = 0; a < 2; ++a) {
    const unsigned short* qrp = qc + (size_t)(qt * BQ + w * 32 + a * 16 + lc) * KD + lq * 8;
    qf[a][0] = *reinterpret_cast<const short8*>(qrp);
    qf[a][1] = *reinterpret_cast<const short8*>(qrp + 32);
    qf[a][2] = *reinterpret_cast<const short8*>(qrp + 64);
  }

  short8 ones;
#pragma unroll
  for (int i = 0; i < 8; ++i) ones[i] = (short)0x3F80;  // bf16 1.0

  const float* bptr = biasc + (size_t)g0 * 64 + lq * 4;

  // cooperative stage of one 64-key group: 20 x 1KB pieces, 5 per wave
  auto stage = [&](int it, int buf) {
    const unsigned short* kg = kc2 + (size_t)(g0 + it) * 6144;
    const unsigned short* vg = vt2 + (size_t)(g0 + it) * 4096;
    unsigned short* lb = lds_kv + buf * 10240;
#pragma unroll
    for (int j5 = 0; j5 < 5; ++j5) {
      int j = w + j5 * 4;
      const unsigned short* src = (j < 12) ? (kg + j * 512) : (vg + (j - 12) * 512);
      __builtin_amdgcn_global_load_lds(
          (const __attribute__((address_space(1))) void*)(src + lane * 8),
          (__attribute__((address_space(3))) void*)(lb + j * 512),
          16, 0, 0);
    }
  };

  floatx4 o[2][4];
#pragma unroll
  for (int a = 0; a < 2; ++a)
#pragma unroll
    for (int nd = 0; nd < 4; ++nd) o[a][nd] = zero;
  floatx4 lacc[2] = {zero, zero};
  int4v pk[2][2];

  // QK + exp2 + pack phase (fills pk; accumulates row sums via ones-MFMA)
  auto qk_phase = [&](const unsigned short* lb, const float* bp) {
    floatx4 b4v[4];
#pragma unroll
    for (int nt = 0; nt < 4; ++nt)
      b4v[nt] = *reinterpret_cast<const floatx4*>(bp + nt * 16);
#pragma unroll
    for (int nt = 0; nt < 4; ++nt) {
      short8 k0 = *reinterpret_cast<const short8*>(lb + (nt * 3 + 0) * 512 + lane * 8);
      short8 k1 = *reinterpret_cast<const short8*>(lb + (nt * 3 + 1) * 512 + lane * 8);
      short8 k2 = *reinterpret_cast<const short8*>(lb + (nt * 3 + 2) * 512 + lane * 8);
#pragma unroll
      for (int a = 0; a < 2; ++a) {
        floatx4 acc = b4v[nt];
        __builtin_amdgcn_s_setprio(1);
        acc = mfma16(k0, qf[a][0], acc);
        acc = mfma16(k1, qf[a][1], acc);
        acc = mfma16(k2, qf[a][2], acc);
        __builtin_amdgcn_s_setprio(0);
        float p0 = __builtin_amdgcn_exp2f(acc[0]);
        float p1 = __builtin_amdgcn_exp2f(acc[1]);
        float p2 = __builtin_amdgcn_exp2f(acc[2]);
        float p3 = __builtin_amdgcn_exp2f(acc[3]);
        pk[a][nt >> 1][(nt & 1) * 2]     = pack_bf16(p0, p1);
        pk[a][nt >> 1][(nt & 1) * 2 + 1] = pack_bf16(p2, p3);
      }
    }
    __builtin_amdgcn_s_setprio(1);
#pragma unroll
    for (int a = 0; a < 2; ++a) {
      lacc[a] = mfma16(__builtin_bit_cast(short8, pk[a][0]), ones, lacc[a]);
      lacc[a] = mfma16(__builtin_bit_cast(short8, pk[a][1]), ones, lacc[a]);
    }
    __builtin_amdgcn_s_setprio(0);
  };

  // PV phase for the pk currently in registers, V frags from given buffer
  auto pv_phase = [&](const unsigned short* lb) {
    __builtin_amdgcn_s_setprio(1);
#pragma unroll
    for (int nd = 0; nd < 4; ++nd) {
      short8 v0 = *reinterpret_cast<const short8*>(lb + 6144 + nd * 512 + lane * 8);
      short8 v1 = *reinterpret_cast<const short8*>(lb + 6144 + (4 + nd) * 512 + lane * 8);
#pragma unroll
      for (int a = 0; a < 2; ++a) {
        o[a][nd] = mfma16(__builtin_bit_cast(short8, pk[a][0]), v0, o[a][nd]);
        o[a][nd] = mfma16(__builtin_bit_cast(short8, pk[a][1]), v1, o[a][nd]);
      }
    }
    __builtin_amdgcn_s_setprio(0);
  };

  // prologue (stage(1) safe even when NIT==1: group g0+1 < NG_PAD, data is pad)
  stage(0, 0);
  __syncthreads();                  // stage(0) landed
  stage(1, 1);
  qk_phase(lds_kv, bptr);
  bptr += BN;

#pragma unroll 1
  for (int it = 1; it < NIT; ++it) {
    // PV for iter it-1: buffer (it-1)&1 still valid (stage(it+1) not yet issued)
    pv_phase(lds_kv + ((it - 1) & 1) * 10240);
    __syncthreads();               // drains PV ds_reads + stage(it) vmcnt
    if (it + 1 < NIT) stage(it + 1, (it + 1) & 1);
    qk_phase(lds_kv + (it & 1) * 10240, bptr);
    bptr += BN;
  }
  pv_phase(lds_kv + ((NIT - 1) & 1) * 10240);

  // epilogue: write partial O and l
  const int pb = qt * NC + chunk;
  float* op = opart + (size_t)pb * BQ * D_V;
#pragma unroll
  for (int a = 0; a < 2; ++a) {
    const int rbase = w * 32 + a * 16 + lq * 4;
#pragma unroll
    for (int nd = 0; nd < 4; ++nd)
#pragma unroll
      for (int r = 0; r < 4; ++r)
        op[(rbase + r) * D_V + nd * 16 + lc] = o[a][nd][r];
    // lacc C-layout: lane (lq,lc) reg r holds l[q-row = lq*4+r] (same across lc)
    if (lc == 0) {
      float* lp = lpart + (size_t)pb * BQ;
#pragma unroll
      for (int r = 0; r < 4; ++r) lp[rbase + r] = lacc[a][r];
    }
  }
}

// ---- final reduction (float4-vectorized) ------------------------------------

template<int NC>
__global__ void reduce_out(const float* __restrict__ opart, const float* __restrict__ lpart,
                           float* __restrict__ out) {
  int t = blockIdx.x * 256 + threadIdx.x;   // 65536 float4s total
  int d4 = t & 15;
  int b = t >> 4;            // q-row 0..4095
  int qt = b >> 7, r = b & 127;
  const floatx4* op4 = reinterpret_cast<const floatx4*>(opart);
  floatx4 os; os[0] = 0.f; os[1] = 0.f; os[2] = 0.f; os[3] = 0.f;
  float ls = 0.f;
#pragma unroll
  for (int c = 0; c < NC; ++c) {
    int row = (qt * NC + c) * BQ + r;
    os += op4[(size_t)row * 16 + d4];
    ls += lpart[row];
  }
  float inv = 1.0f / ls;
  reinterpret_cast<floatx4*>(out)[t] = os * inv;
}

// ---- launcher ---------------------------------------------------------------

template<int NC>
static void launch_all(const float* query, const float* context, const float* keys,
                       const float* values, const float* contexts, const float* ts,
                       const int* used, float* out, char* ws, hipStream_t stream) {
  unsigned short* qc   = (unsigned short*)ws;  ws += (size_t)B_TOT * KD * 2;
  unsigned short* kc2c = (unsigned short*)ws;  ws += (size_t)NG_PAD * 6144 * 2;
  unsigned short* vt2c = (unsigned short*)ws;  ws += (size_t)NG_PAD * 4096 * 2;
  float* biasc = (float*)ws;                   ws += (size_t)NG_PAD * 64 * 4;
  int* off     = (int*)ws;                     ws += (size_t)NGRP * 4;
  unsigned long long* masks = (unsigned long long*)ws;  ws += (size_t)NGRP * 8;
  int* gtotal  = (int*)ws;                     ws += 16;
  float* opart = (float*)ws;                   ws += (size_t)NC * B_TOT * D_V * 4;
  float* lpart = (float*)ws;

  scan_used<<<1, 1024, 0, stream>>>(used, off, masks, gtotal);

  prep2<<<NG_PAD + NB_Q, 256, 0, stream>>>(
      query, context, keys, contexts, values, ts, off, masks, gtotal,
      qc, kc2c, vt2c, biasc);

  dim3 grid(NQT, NC);
  flash_kernel<NC><<<grid, 256, 0, stream>>>(qc, kc2c, vt2c, biasc, gtotal,
                                             opart, lpart);

  reduce_out<NC><<<(B_TOT * D_V / 4) / 256, 256, 0, stream>>>(opart, lpart, out);
}

extern "C" void kernel_launch(void* const* d_in, const int* in_sizes, int n_in,
                              void* d_out, int out_size, void* d_ws, size_t ws_size,
                              hipStream_t stream) {
  const float* query    = (const float*)d_in[0];
  const float* context  = (const float*)d_in[1];
  const float* keys     = (const float*)d_in[2];
  const float* values   = (const float*)d_in[3];
  const float* contexts = (const float*)d_in[4];
  const float* ts       = (const float*)d_in[5];
  const int*   used     = (const int*)d_in[6];
  float* out = (float*)d_out;
  char* ws = (char*)d_ws;

  const size_t fixed = (size_t)B_TOT * KD * 2 + (size_t)NG_PAD * 6144 * 2 +
                       (size_t)NG_PAD * 4096 * 2 + (size_t)NG_PAD * 64 * 4 +
                       (size_t)NGRP * 4 + (size_t)NGRP * 8 + 16;
  const size_t need32 = fixed + 32ull * ((size_t)B_TOT * D_V * 4 + (size_t)B_TOT * 4);

  if (ws_size >= need32)
    launch_all<32>(query, context, keys, values, contexts, ts, used, out, ws, stream);
  else
    launch_all<16>(query, context, keys, values, contexts, ts, used, out, ws, stream);
}

// Round 7
// 167.057 us; speedup vs baseline: 1.2672x; 1.0696x over previous
//
#include <hip/hip_runtime.h>
#include <hip/hip_bf16.h>

// Problem constants
#define B_TOT  4096
#define M_TOT  65536
#define D_V    64
#define KD     96            // 64 (keys) + 32 (0.5*contexts); Q side pre-scaled by log2e
#define BQ     128           // q rows per block (4 waves x 32)
#define BN     64            // keys per inner tile
#define NQT    (B_TOT / BQ)  // 32
#define SHIFT2 23.0f         // fixed softmax shift in exp2 domain
#define NGRP   1024          // source 64-slot groups
#define NG_PAD 1056          // compacted group capacity (>= NC*ceil(NGRP/NC) for NC=16,32)

using short8   = __attribute__((ext_vector_type(8))) short;
using floatx4  = __attribute__((ext_vector_type(4))) float;
using int4v    = __attribute__((ext_vector_type(4))) int;

static __device__ __forceinline__ unsigned short f2bf(float f) {
  return __builtin_bit_cast(unsigned short, __float2bfloat16(f));
}

// truncation pack: two f32 -> one dword of bf16 (lo=a, hi=b), single v_perm_b32.
// Truncation bias cancels in the softmax ratio (verified: absmax 1.5e-5).
static __device__ __forceinline__ int pack_bf16(float a, float b) {
  return (int)__builtin_amdgcn_perm(__builtin_bit_cast(unsigned, b),
                                    __builtin_bit_cast(unsigned, a),
                                    0x07060302u);
}

static __device__ __forceinline__ floatx4 mfma16(short8 a, short8 b, floatx4 c) {
  return __builtin_amdgcn_mfma_f32_16x16x32_bf16(a, b, c, 0, 0, 0);
}

#define LOG2E 1.4426950408889634f

// ---- kernel 1: count + scan used slots --------------------------------------
// 1 block x 1024 threads. R7: 8-deep load batching — 8 independent coalesced
// loads issued back-to-back, THEN 8 ballots. Cuts the dependent-HBM-latency
// chain from 64 to 8 round trips (~25 us -> ~4 us on one block).
// Masked slots contribute EXACTLY 0 to softmax (exp2(-1e9) underflows to 0 in
// fp32, same as the reference), so compacting to used slots is numerically
// exact up to fp32 summation order (~1e-7).

__global__ __launch_bounds__(1024) void
scan_used(const int* __restrict__ used, int* __restrict__ off,
          unsigned long long* __restrict__ masks, int* __restrict__ gtotal)
{
  __shared__ int s[NGRP];
  const int t = threadIdx.x;
  const int w = t >> 6, l = t & 63;
#pragma unroll 1
  for (int i0 = 0; i0 < 64; i0 += 8) {
    int v[8];
#pragma unroll
    for (int k = 0; k < 8; ++k)
      v[k] = used[(i0 + k) * 1024 + w * 64 + l];   // g = (i0+k)*16 + w
#pragma unroll
    for (int k = 0; k < 8; ++k) {
      unsigned long long m = __ballot(v[k] != 0);
      int g = (i0 + k) * 16 + w;
      if (l == 0) { masks[g] = m; s[g] = __popcll(m); }
    }
  }
  __syncthreads();
  const int c0 = s[t];
#pragma unroll 1
  for (int st = 1; st < NGRP; st <<= 1) {
    int add = (t >= st) ? s[t - st] : 0;
    __syncthreads();
    s[t] += add;
    __syncthreads();
  }
  off[t] = s[t] - c0;
  if (t == NGRP - 1) *gtotal = s[t];
}

// ---- kernel 2: gather-prep into compacted fragment-linear layouts -----------
// blocks [0, NG_PAD): compacted K/ctx/V/bias dest groups (gather via off+masks)
// blocks [NG_PAD, NG_PAD+NB_Q): qc (unchanged)
// R7: blocks >= glim = NC*ceil(Gtot/NC) (never read by flash) return with no
// work; full-pad groups in [Gtot, glim) zero-fill without gathering.

#define NB_Q 1536

template<int NC>
__global__ __launch_bounds__(256) void
prep2(const float* __restrict__ q, const float* __restrict__ ctx,
      const float* __restrict__ keys, const float* __restrict__ ctxs,
      const float* __restrict__ vals, const float* __restrict__ ts,
      const int* __restrict__ off, const unsigned long long* __restrict__ masks,
      const int* __restrict__ gtotal,
      unsigned short* __restrict__ qc, unsigned short* __restrict__ kc2,
      unsigned short* __restrict__ vt2, float* __restrict__ biasc)
{
  const int bid = blockIdx.x;
  const int t = threadIdx.x;

  if (bid < NG_PAD) {
    const int gq = bid;              // dest group
    const int total = *gtotal;
    const int Gtot = (total + 63) >> 6;
    int GPC = (Gtot + NC - 1) / NC;
    if (GPC < 1) GPC = 1;
    const int glim = NC * GPC;       // groups flash will actually read
    if (gq >= glim) return;

    if (gq * 64 >= total) {          // full pad group: zeros + -1e9 bias
      short8 z8;
#pragma unroll
      for (int j = 0; j < 8; ++j) z8[j] = 0;
      unsigned short* outk = kc2 + (size_t)gq * 6144;
#pragma unroll
      for (int p = 0; p < 3; ++p)
        *reinterpret_cast<short8*>(outk + p * 2048 + t * 8) = z8;
      unsigned short* outv = vt2 + (size_t)gq * 4096;
#pragma unroll
      for (int p = 0; p < 2; ++p)
        *reinterpret_cast<short8*>(outv + p * 2048 + t * 8) = z8;
      if (t < 64) biasc[gq * 64 + t] = -1e9f;
      return;
    }

    __shared__ float lk[64 * 65];    // K rows; reused for V rows
    __shared__ float lx[64 * 33];    // ctx rows
    __shared__ int sidx[64];

    // source index for each of this dest group's 64 slots
    if (t < 64) {
      int mP = gq * 64 + t, src = -1;
      if (mP < total) {
        int lo = 0, hi = NGRP - 1;
#pragma unroll 1
        while (lo < hi) {            // last g with off[g] <= mP
          int mid = (lo + hi + 1) >> 1;
          int ov = off[mid];
          if (ov <= mP) lo = mid; else hi = mid - 1;
        }
        int r = mP - off[lo];
        unsigned long long x = masks[lo];
#pragma unroll 1
        for (int k = 0; k < r; ++k) x &= x - 1;   // select r-th set bit
        src = lo * 64 + (int)__builtin_ctzll(x);
      }
      sidx[t] = src;
    }
    __syncthreads();

    const floatx4* kb4 = reinterpret_cast<const floatx4*>(keys);
    const floatx4* xb4 = reinterpret_cast<const floatx4*>(ctxs);
    const floatx4* vb4 = reinterpret_cast<const floatx4*>(vals);
    floatx4 z4; z4[0] = 0.f; z4[1] = 0.f; z4[2] = 0.f; z4[3] = 0.f;

    // gather K rows (64x64 f32) + ctx rows (64x32 f32); pad rows -> 0
#pragma unroll
    for (int i = 0; i < 4; ++i) {
      int idx4 = i * 256 + t;
      int row = idx4 >> 4, col = idx4 & 15;
      int s = sidx[row];
      floatx4 v = (s >= 0) ? kb4[(size_t)s * 16 + col] : z4;
      lk[row * 65 + col * 4 + 0] = v[0];
      lk[row * 65 + col * 4 + 1] = v[1];
      lk[row * 65 + col * 4 + 2] = v[2];
      lk[row * 65 + col * 4 + 3] = v[3];
    }
#pragma unroll
    for (int i = 0; i < 2; ++i) {
      int idx4 = i * 256 + t;
      int row = idx4 >> 3, col = idx4 & 7;
      int s = sidx[row];
      floatx4 v = (s >= 0) ? xb4[(size_t)s * 8 + col] : z4;
      lx[row * 33 + col * 4 + 0] = v[0];
      lx[row * 33 + col * 4 + 1] = v[1];
      lx[row * 33 + col * 4 + 2] = v[2];
      lx[row * 33 + col * 4 + 3] = v[3];
    }
    __syncthreads();

    // pack kc2 fragment-linear (same mapping as before, dest group gq)
    unsigned short* outk = kc2 + (size_t)gq * 6144;
#pragma unroll
    for (int p = 0; p < 3; ++p) {
      int o = p * 2048 + t * 8;
      int c = o >> 9;
      int lane = (o >> 3) & 63;
      int lqq = lane >> 4, lcc = lane & 15;
      int nt = c / 3, s = c - nt * 3;
      int ml = nt * 16 + lcc;
      short8 v;
#pragma unroll
      for (int j = 0; j < 8; ++j) {
        int kk = s * 32 + lqq * 8 + j;
        float f = (kk < 64) ? lk[ml * 65 + kk] : lx[ml * 33 + (kk - 64)];
        v[j] = (short)f2bf(f);
      }
      *reinterpret_cast<short8*>(outk + o) = v;
    }
    // bias for this dest group (pad -> -1e9 -> exp2 -> 0)
    if (t < 64) {
      int s = sidx[t];
      biasc[gq * 64 + t] =
          (s >= 0) ? (LOG2E * 0.3f * __expf(-0.1f * (1.0f - ts[s])) - SHIFT2)
                   : -1e9f;
    }
    __syncthreads();   // all kc2-pack reads of lk done before V overwrites it

    // gather V rows into lk
#pragma unroll
    for (int i = 0; i < 4; ++i) {
      int idx4 = i * 256 + t;
      int row = idx4 >> 4, col = idx4 & 15;
      int s = sidx[row];
      floatx4 v = (s >= 0) ? vb4[(size_t)s * 16 + col] : z4;
      lk[row * 65 + col * 4 + 0] = v[0];
      lk[row * 65 + col * 4 + 1] = v[1];
      lk[row * 65 + col * 4 + 2] = v[2];
      lk[row * 65 + col * 4 + 3] = v[3];
    }
    __syncthreads();

    // pack vt2 (B-operand of P*V, key-permutation baked in), dest group gq
    unsigned short* outv = vt2 + (size_t)gq * 4096;
#pragma unroll
    for (int p = 0; p < 2; ++p) {
      int o = p * 2048 + t * 8;
      int c2 = o >> 9;
      int lane = (o >> 3) & 63;
      int lqq = lane >> 4, lcc = lane & 15;
      int h = c2 >> 2, nd = c2 & 3;
      short8 wv;
#pragma unroll
      for (int j = 0; j < 8; ++j) {
        int mloc = h * 32 + ((j < 4) ? (lqq * 4 + j) : (16 + lqq * 4 + (j - 4)));
        wv[j] = (short)f2bf(lk[mloc * 65 + nd * 16 + lcc]);
      }
      *reinterpret_cast<short8*>(outv + o) = wv;
    }
  } else {
    int tt = (bid - NG_PAD) * 256 + t;     // 4096*96
    int b = tt / KD, j = tt % KD;
    float v = (j < 64) ? q[b * 64 + j] : 0.5f * ctx[b * 32 + (j - 64)];
    qc[tt] = f2bf(v * LOG2E);
  }
}

// ---- flash attention main kernel -------------------------------------------
// grid (NQT, NC); block 256 = 4 waves; each wave owns 32 q rows (2 B-frags).
// Runs over the COMPACTED slot stream: NIT = GPC = ceil(Gtot/NC) groups per
// chunk, read from gtotal at runtime (uniform across the grid; grid dims
// static -> graph-capture safe). Pad groups contribute exact zeros.
// Software pipeline + setprio (R5) unchanged.

template<int NC>
__global__ __launch_bounds__(256, 4) void
flash_kernel(const unsigned short* __restrict__ qc,
             const unsigned short* __restrict__ kc2,
             const unsigned short* __restrict__ vt2,
             const float* __restrict__ biasc,
             const int* __restrict__ gtotal,
             float* __restrict__ opart, float* __restrict__ lpart)
{
  __shared__ __align__(16) unsigned short lds_kv[2 * 10240];  // 40960 B
  const int qt    = blockIdx.x;
  const int chunk = blockIdx.y;
  const int tid   = threadIdx.x;
  const int w     = tid >> 6;
  const int lane  = tid & 63;
  const int lq    = lane >> 4;
  const int lc    = lane & 15;

  const int total = *gtotal;
  const int Gtot  = (total + 63) >> 6;
  int GPC = (Gtot + NC - 1) / NC;
  if (GPC < 1) GPC = 1;
  const int NIT = GPC;                 // 64-key tiles for this chunk
  const int g0  = chunk * GPC;

  floatx4 zero; zero[0] = 0.f; zero[1] = 0.f; zero[2] = 0.f; zero[3] = 0.f;

  // Q fragments (B-operand): q-rows qt*128 + w*32 + a*16 + lc
  short8 qf[2][3];
#pragma unroll
  for (int a = 0; a < 2; ++a) {
    const unsigned short* qrp = qc + (size_t)(qt * BQ + w * 32 + a * 16 + lc) * KD + lq * 8;
    qf[a][0] = *reinterpret_cast<const short8*>(qrp);
    qf[a][1] = *reinterpret_cast<const short8*>(qrp + 32);
    qf[a][2] = *reinterpret_cast<const short8*>(qrp + 64);
  }

  short8 ones;
#pragma unroll
  for (int i = 0; i < 8; ++i) ones[i] = (short)0x3F80;  // bf16 1.0

  const float* bptr = biasc + (size_t)g0 * 64 + lq * 4;

  // cooperative stage of one 64-key group: 20 x 1KB pieces, 5 per wave
  auto stage = [&](int it, int buf) {
    const unsigned short* kg = kc2 + (size_t)(g0 + it) * 6144;
    const unsigned short* vg = vt2 + (size_t)(g0 + it) * 4096;
    unsigned short* lb = lds_kv + buf * 10240;
#pragma unroll
    for (int j5 = 0; j5 < 5; ++j5) {
      int j = w + j5 * 4;
      const unsigned short* src = (j < 12) ? (kg + j * 512) : (vg + (j - 12) * 512);
      __builtin_amdgcn_global_load_lds(
          (const __attribute__((address_space(1))) void*)(src + lane * 8),
          (__attribute__((address_space(3))) void*)(lb + j * 512),
          16, 0, 0);
    }
  };

  floatx4 o[2][4];
#pragma unroll
  for (int a = 0; a < 2; ++a)
#pragma unroll
    for (int nd = 0; nd < 4; ++nd) o[a][nd] = zero;
  floatx4 lacc[2] = {zero, zero};
  int4v pk[2][2];

  // QK + exp2 + pack phase (fills pk; accumulates row sums via ones-MFMA)
  auto qk_phase = [&](const unsigned short* lb, const float* bp) {
    floatx4 b4v[4];
#pragma unroll
    for (int nt = 0; nt < 4; ++nt)
      b4v[nt] = *reinterpret_cast<const floatx4*>(bp + nt * 16);
#pragma unroll
    for (int nt = 0; nt < 4; ++nt) {
      short8 k0 = *reinterpret_cast<const short8*>(lb + (nt * 3 + 0) * 512 + lane * 8);
      short8 k1 = *reinterpret_cast<const short8*>(lb + (nt * 3 + 1) * 512 + lane * 8);
      short8 k2 = *reinterpret_cast<const short8*>(lb + (nt * 3 + 2) * 512 + lane * 8);
#pragma unroll
      for (int a = 0; a < 2; ++a) {
        floatx4 acc = b4v[nt];
        __builtin_amdgcn_s_setprio(1);
        acc = mfma16(k0, qf[a][0], acc);
        acc = mfma16(k1, qf[a][1], acc);
        acc = mfma16(k2, qf[a][2], acc);
        __builtin_amdgcn_s_setprio(0);
        float p0 = __builtin_amdgcn_exp2f(acc[0]);
        float p1 = __builtin_amdgcn_exp2f(acc[1]);
        float p2 = __builtin_amdgcn_exp2f(acc[2]);
        float p3 = __builtin_amdgcn_exp2f(acc[3]);
        pk[a][nt >> 1][(nt & 1) * 2]     = pack_bf16(p0, p1);
        pk[a][nt >> 1][(nt & 1) * 2 + 1] = pack_bf16(p2, p3);
      }
    }
    __builtin_amdgcn_s_setprio(1);
#pragma unroll
    for (int a = 0; a < 2; ++a) {
      lacc[a] = mfma16(__builtin_bit_cast(short8, pk[a][0]), ones, lacc[a]);
      lacc[a] = mfma16(__builtin_bit_cast(short8, pk[a][1]), ones, lacc[a]);
    }
    __builtin_amdgcn_s_setprio(0);
  };

  // PV phase for the pk currently in registers, V frags from given buffer
  auto pv_phase = [&](const unsigned short* lb) {
    __builtin_amdgcn_s_setprio(1);
#pragma unroll
    for (int nd = 0; nd < 4; ++nd) {
      short8 v0 = *reinterpret_cast<const short8*>(lb + 6144 + nd * 512 + lane * 8);
      short8 v1 = *reinterpret_cast<const short8*>(lb + 6144 + (4 + nd) * 512 + lane * 8);
#pragma unroll
      for (int a = 0; a < 2; ++a) {
        o[a][nd] = mfma16(__builtin_bit_cast(short8, pk[a][0]), v0, o[a][nd]);
        o[a][nd] = mfma16(__builtin_bit_cast(short8, pk[a][1]), v1, o[a][nd]);
      }
    }
    __builtin_amdgcn_s_setprio(0);
  };

  // prologue (stage(1) safe even when NIT==1: group g0+1 <= NC*GPC < NG_PAD,
  // in-bounds; its data is only consumed when NIT >= 2)
  stage(0, 0);
  __syncthreads();                  // stage(0) landed
  stage(1, 1);
  qk_phase(lds_kv, bptr);
  bptr += BN;

#pragma unroll 1
  for (int it = 1; it < NIT; ++it) {
    // PV for iter it-1: buffer (it-1)&1 still valid (stage(it+1) not yet issued)
    pv_phase(lds_kv + ((it - 1) & 1) * 10240);
    __syncthreads();               // drains PV ds_reads + stage(it) vmcnt
    if (it + 1 < NIT) stage(it + 1, (it + 1) & 1);
    qk_phase(lds_kv + (it & 1) * 10240, bptr);
    bptr += BN;
  }
  pv_phase(lds_kv + ((NIT - 1) & 1) * 10240);

  // epilogue: write partial O and l
  const int pb = qt * NC + chunk;
  float* op = opart + (size_t)pb * BQ * D_V;
#pragma unroll
  for (int a = 0; a < 2; ++a) {
    const int rbase = w * 32 + a * 16 + lq * 4;
#pragma unroll
    for (int nd = 0; nd < 4; ++nd)
#pragma unroll
      for (int r = 0; r < 4; ++r)
        op[(rbase + r) * D_V + nd * 16 + lc] = o[a][nd][r];
    // lacc C-layout: lane (lq,lc) reg r holds l[q-row = lq*4+r] (same across lc)
    if (lc == 0) {
      float* lp = lpart + (size_t)pb * BQ;
#pragma unroll
      for (int r = 0; r < 4; ++r) lp[rbase + r] = lacc[a][r];
    }
  }
}

// ---- final reduction (float4-vectorized) ------------------------------------

template<int NC>
__global__ void reduce_out(const float* __restrict__ opart, const float* __restrict__ lpart,
                           float* __restrict__ out) {
  int t = blockIdx.x * 256 + threadIdx.x;   // 65536 float4s total
  int d4 = t & 15;
  int b = t >> 4;            // q-row 0..4095
  int qt = b >> 7, r = b & 127;
  const floatx4* op4 = reinterpret_cast<const floatx4*>(opart);
  floatx4 os; os[0] = 0.f; os[1] = 0.f; os[2] = 0.f; os[3] = 0.f;
  float ls = 0.f;
#pragma unroll
  for (int c = 0; c < NC; ++c) {
    int row = (qt * NC + c) * BQ + r;
    os += op4[(size_t)row * 16 + d4];
    ls += lpart[row];
  }
  float inv = 1.0f / ls;
  reinterpret_cast<floatx4*>(out)[t] = os * inv;
}

// ---- launcher ---------------------------------------------------------------

template<int NC>
static void launch_all(const float* query, const float* context, const float* keys,
                       const float* values, const float* contexts, const float* ts,
                       const int* used, float* out, char* ws, hipStream_t stream) {
  unsigned short* qc   = (unsigned short*)ws;  ws += (size_t)B_TOT * KD * 2;
  unsigned short* kc2c = (unsigned short*)ws;  ws += (size_t)NG_PAD * 6144 * 2;
  unsigned short* vt2c = (unsigned short*)ws;  ws += (size_t)NG_PAD * 4096 * 2;
  float* biasc = (float*)ws;                   ws += (size_t)NG_PAD * 64 * 4;
  int* off     = (int*)ws;                     ws += (size_t)NGRP * 4;
  unsigned long long* masks = (unsigned long long*)ws;  ws += (size_t)NGRP * 8;
  int* gtotal  = (int*)ws;                     ws += 16;
  float* opart = (float*)ws;                   ws += (size_t)NC * B_TOT * D_V * 4;
  float* lpart = (float*)ws;

  scan_used<<<1, 1024, 0, stream>>>(used, off, masks, gtotal);

  prep2<NC><<<NG_PAD + NB_Q, 256, 0, stream>>>(
      query, context, keys, contexts, values, ts, off, masks, gtotal,
      qc, kc2c, vt2c, biasc);

  dim3 grid(NQT, NC);
  flash_kernel<NC><<<grid, 256, 0, stream>>>(qc, kc2c, vt2c, biasc, gtotal,
                                             opart, lpart);

  reduce_out<NC><<<(B_TOT * D_V / 4) / 256, 256, 0, stream>>>(opart, lpart, out);
}

extern "C" void kernel_launch(void* const* d_in, const int* in_sizes, int n_in,
                              void* d_out, int out_size, void* d_ws, size_t ws_size,
                              hipStream_t stream) {
  const float* query    = (const float*)d_in[0];
  const float* context  = (const float*)d_in[1];
  const float* keys     = (const float*)d_in[2];
  const float* values   = (const float*)d_in[3];
  const float* contexts = (const float*)d_in[4];
  const float* ts       = (const float*)d_in[5];
  const int*   used     = (const int*)d_in[6];
  float* out = (float*)d_out;
  char* ws = (char*)d_ws;

  const size_t fixed = (size_t)B_TOT * KD * 2 + (size_t)NG_PAD * 6144 * 2 +
                       (size_t)NG_PAD * 4096 * 2 + (size_t)NG_PAD * 64 * 4 +
                       (size_t)NGRP * 4 + (size_t)NGRP * 8 + 16;
  const size_t need32 = fixed + 32ull * ((size_t)B_TOT * D_V * 4 + (size_t)B_TOT * 4);

  if (ws_size >= need32)
    launch_all<32>(query, context, keys, values, contexts, ts, used, out, ws, stream);
  else
    launch_all<16>(query, context, keys, values, contexts, ts, used, out, ws, stream);
}